// Round 9
// baseline (717.939 us; speedup 1.0000x reference)
//
#include <hip/hip_runtime.h>
#include <hip/hip_bf16.h>

#define T_TASKS 8
#define B_ROWS 4096
#define PADROWS 4224      // +128 so partial-tile A loads stay in-bounds
#define BM 128
#define BN 64
#define BK 32
#define MAXTILES 40       // sum over tasks of ceil(cnt/BM) <= T + B/BM = 40

typedef __attribute__((ext_vector_type(4))) float f32x4;
typedef __attribute__((ext_vector_type(8))) short bf16x8;

#define GLOAD_LDS16(g, l) __builtin_amdgcn_global_load_lds( \
    (const __attribute__((address_space(1))) void*)(g), \
    (__attribute__((address_space(3))) void*)(l), 16, 0, 0)

#define WAITV10() asm volatile("s_waitcnt vmcnt(10)" ::: "memory")
#define BAR() do { __builtin_amdgcn_s_barrier(); __builtin_amdgcn_sched_barrier(0); } while (0)

__device__ __forceinline__ unsigned short f32_to_bf16(float f) {
    union { float f; unsigned int u; } v; v.f = f;
    unsigned int r = v.u + 0x7FFF + ((v.u >> 16) & 1);  // RNE
    return (unsigned short)(r >> 16);
}

__device__ __forceinline__ unsigned int pack2_bf16(float lo, float hi) {
    __hip_bfloat162 h = __float22bfloat162_rn(make_float2(lo, hi));  // lo -> low 16 bits
    union { __hip_bfloat162 h; unsigned int u; } c; c.h = h;
    return c.u;
}

// ---------------- setup: counting sort by task + tile table ----------------
__global__ void setup_kernel(const int* __restrict__ task, int* __restrict__ perm,
                             int* __restrict__ offs, int* __restrict__ table) {
    __shared__ int cnt[T_TASKS];
    __shared__ int cur[T_TASKS];
    int tid = threadIdx.x;
    if (tid < T_TASKS) cnt[tid] = 0;
    __syncthreads();
    for (int b = tid; b < B_ROWS; b += blockDim.x)
        atomicAdd(&cnt[task[b]], 1);
    __syncthreads();
    if (tid == 0) {
        int o = 0;
        for (int t = 0; t < T_TASKS; ++t) { offs[t] = o; cur[t] = o; o += cnt[t]; }
        offs[T_TASKS] = o;
        int s = 0;
        for (int t = 0; t < T_TASKS; ++t) {
            int nt = (cnt[t] + BM - 1) / BM;
            for (int j = 0; j < nt; ++j) table[s++] = (t << 16) | j;
        }
        for (; s < MAXTILES; ++s) table[s] = -1;
    }
    __syncthreads();
    for (int b = tid; b < B_ROWS; b += blockDim.x) {
        int t = task[b];
        int pos = atomicAdd(&cur[t], 1);
        perm[pos] = b;
    }
}

// ---------------- permute + cast x -> bf16 ----------------
__global__ void permute_cast_kernel(const float* __restrict__ x, const int* __restrict__ perm,
                                    unsigned short* __restrict__ xp) {
    int rowp = blockIdx.x;
    int src = perm[rowp];
    const float4* xin = reinterpret_cast<const float4*>(x + (size_t)src * 1024);
    unsigned short* dst = xp + (size_t)rowp * 1024;
    int c4 = threadIdx.x;
    float4 v = xin[c4];
    ushort4 o;
    o.x = f32_to_bf16(v.x); o.y = f32_to_bf16(v.y);
    o.z = f32_to_bf16(v.z); o.w = f32_to_bf16(v.w);
    *reinterpret_cast<ushort4*>(dst + c4 * 4) = o;
}

// ---------------- VAE reparameterization ----------------
__global__ void vae_kernel(const float* __restrict__ scat, const float* __restrict__ eps,
                           const int* __restrict__ perm, unsigned short* __restrict__ z) {
    int rowp = blockIdx.x;
    int c = threadIdx.x;
    int src = perm[rowp];
    float mu = scat[(size_t)rowp * 512 + c];
    float ls = scat[(size_t)rowp * 512 + 256 + c];
    float e  = eps[(size_t)src * 256 + c];
    z[(size_t)rowp * 256 + c] = f32_to_bf16(mu + __expf(ls) * e);
}

// ---------------- grouped GEMM, f32 [K][N] weights, counted-vmcnt pipeline ----------------
// A: bf16 [rowp][K] grouped (padded rows), global_load_lds, src-XOR ((row>>1)&3), linear LDS.
// B: f32 [t][K][N]: 8 k-strided dwords/lane (wave = 64 consecutive n -> coalesced),
//    cvt_pk -> ds_write_b128 at slot c^((n>>1)&3)  (R8-proven, 0 conflicts).
// NEW (T3/T4): 3 LDS buffers (36 KB, 4 blocks/CU), 2 B-reg banks, per step:
//    vmcnt(10) -> s_barrier -> compute(j) -> write_b(j+1) -> load_b(j+3) -> stage_a(j+2)
// vmcnt NEVER drains to 0 in the loop; A-DMA and B-regs get ~2 steps of latency budget.
// Buffer safety at one-step wave skew: writes target (j+1)%3 / (j+2)%3, reader at (j-1)%3
// only pre-compute -> after the barrier reader is at j%3; all distinct mod 3.
// Tail: k0 clamped to K-BK (redundant L2-hit loads keep vmcnt counts constant).
// MODE 0: relu -> bf16 store; MODE 1: f32 store; MODE 2: sigmoid -> f32 scatter via perm
template<int MODE>
__global__ __launch_bounds__(256, 4)
void gemm9_kernel(const unsigned short* __restrict__ A,
                  const float* __restrict__ W,
                  const float* __restrict__ bias, void* __restrict__ dst,
                  const int* __restrict__ offs, const int* __restrict__ table,
                  const int* __restrict__ perm,
                  int K, int N, int ldd, int Btot, int GX)
{
    __shared__ unsigned short As[3][BM * BK];   // 8 KB each
    __shared__ unsigned short Bs[3][BN * BK];   // 4 KB each  (36 KB total)

    const int bxh = blockIdx.x;
    const int tid = threadIdx.x;

    // XCD-chunked bijective bx remap (GX % 8 == 0 for all launches here)
    int bx = (bxh & 7) * (GX >> 3) + (bxh >> 3);

    int t, mtile, off, cnt;
    if (table != nullptr) {
        int v = table[bx];
        if (v < 0) return;
        t = v >> 16; mtile = v & 0xFFFF;
        off = offs[t]; cnt = offs[t + 1] - off;
    } else {
        t = 0; mtile = bx; off = 0; cnt = Btot;
    }
    const int n0 = blockIdx.y * BN;

    const int lane = tid & 63;
    const int wave = tid >> 6;
    const int wr = wave >> 1, wc = wave & 1;

    // ---- A staging geometry (R6/R8-proven) ----
    const int rl   = lane >> 2;                 // 0..15 row within 16-row line
    const int csrc = ((lane & 3) ^ ((rl >> 1) & 3)) * 8;
    const unsigned short* Ab = A + ((size_t)(off + mtile * BM + rl)) * K + csrc;

    // ---- B staging geometry: n = lane, k-chunk = wave ----
    const int bn = lane;                        // 0..63
    const int bc = wave;                        // 0..3 -> k rows bc*8..+7
    const float* Wb = W + (size_t)t * K * N + n0 + bn;
    const int bslot = (bc ^ ((bn >> 1) & 3)) * 8;   // ushort offset of 16B slot
    float brA[8], brB[8];

    const int nsteps = K / BK;
    const int kmax = K - BK;
    auto kc = [&](int s) { int k = s * BK; return k > kmax ? kmax : k; };

    auto stage_a = [&](int buf, int k0) {
        #pragma unroll
        for (int jj = 0; jj < 2; ++jj) {
            int j = wave * 2 + jj;              // 0..7: A 16-row line
            GLOAD_LDS16(Ab + (size_t)(j * 16) * K + k0, &As[buf][j * 512]);
        }
    };
    auto load_b = [&](float (&br)[8], int k0) {
        const float* p = Wb + (size_t)(k0 + bc * 8) * N;
        #pragma unroll
        for (int j = 0; j < 8; ++j)
            br[j] = p[(size_t)j * N];
    };
    auto write_b = [&](int buf, float (&br)[8]) {
        uint4 wv;
        wv.x = pack2_bf16(br[0], br[1]);
        wv.y = pack2_bf16(br[2], br[3]);
        wv.z = pack2_bf16(br[4], br[5]);
        wv.w = pack2_bf16(br[6], br[7]);
        *reinterpret_cast<uint4*>(&Bs[buf][bn * 32 + bslot]) = wv;
    };

    f32x4 acc[4][2];
    #pragma unroll
    for (int m = 0; m < 4; ++m)
        #pragma unroll
        for (int n = 0; n < 2; ++n)
            acc[m][n] = (f32x4){0.f, 0.f, 0.f, 0.f};

    auto compute = [&](int buf) {
        bf16x8 af[4], bfr[2];
        #pragma unroll
        for (int m = 0; m < 4; ++m) {
            int rf = wr * 64 + m * 16 + (lane & 15);
            af[m] = *reinterpret_cast<const bf16x8*>(
                &As[buf][rf * 32 + (((lane >> 4) ^ ((rf >> 1) & 3)) * 8)]);
        }
        #pragma unroll
        for (int n = 0; n < 2; ++n) {
            int nf = wc * 32 + n * 16 + (lane & 15);
            bfr[n] = *reinterpret_cast<const bf16x8*>(
                &Bs[buf][nf * 32 + (((lane >> 4) ^ ((nf >> 1) & 3)) * 8)]);
        }
        #pragma unroll
        for (int m = 0; m < 4; ++m)
            #pragma unroll
            for (int n = 0; n < 2; ++n)
                acc[m][n] = __builtin_amdgcn_mfma_f32_16x16x32_bf16(af[m], bfr[n], acc[m][n], 0, 0, 0);
    };

    // ---- prologue: issue order fixes vmcnt arithmetic (see header) ----
    load_b(brA, kc(0));         // 8  (bank0 = even steps)
    stage_a(0, kc(0));          // 2
    load_b(brB, kc(1));         // 8  (bank1 = odd steps)
    stage_a(1, kc(1));          // 2
    write_b(0, brA);            // compiler auto-waits lb(0)
    load_b(brA, kc(2));         // 8  -> outstanding 20 entering loop

    // ---- main loop, unrolled x2 for static reg banks (nsteps is even) ----
    for (int j = 0; j < nsteps; j += 2) {
        // step j (even): consume brB for wb(j+1), refill brB with b(j+3)
        WAITV10(); BAR();
        compute(j % 3);
        write_b((j + 1) % 3, brB);
        load_b(brB, kc(j + 3));
        stage_a((j + 2) % 3, kc(j + 2));
        // step j+1 (odd): consume brA for wb(j+2), refill brA with b(j+4)
        WAITV10(); BAR();
        compute((j + 1) % 3);
        write_b((j + 2) % 3, brA);
        load_b(brA, kc(j + 4));
        stage_a((j + 3) % 3, kc(j + 3));
    }

    // ---- epilogue ----
    const float* bt = bias + (size_t)t * N;
    #pragma unroll
    for (int n = 0; n < 2; ++n) {
        int col = n0 + wc * 32 + n * 16 + (lane & 15);
        float bv = bt[col];
        #pragma unroll
        for (int m = 0; m < 4; ++m) {
            int rbase = mtile * BM + wr * 64 + m * 16 + ((lane >> 4) << 2);
            #pragma unroll
            for (int j = 0; j < 4; ++j) {
                int local = rbase + j;
                if (local >= cnt) continue;
                float v = acc[m][n][j] + bv;
                if (MODE == 0) {
                    ((unsigned short*)dst)[(size_t)(off + local) * ldd + col] =
                        f32_to_bf16(fmaxf(v, 0.f));
                } else if (MODE == 1) {
                    ((float*)dst)[(size_t)(off + local) * ldd + col] = v;
                } else {
                    int grow = perm[off + local];
                    ((float*)dst)[(size_t)grow * ldd + col] = 1.f / (1.f + __expf(-v));
                }
            }
        }
    }
}

extern "C" void kernel_launch(void* const* d_in, const int* in_sizes, int n_in,
                              void* d_out, int out_size, void* d_ws, size_t ws_size,
                              hipStream_t stream) {
    const float* x      = (const float*)d_in[0];
    const int*   task   = (const int*)d_in[1];
    const float* eps    = (const float*)d_in[2];
    const float* enc_W1 = (const float*)d_in[3];
    const float* enc_b1 = (const float*)d_in[4];
    const float* enc_W2 = (const float*)d_in[5];
    const float* enc_b2 = (const float*)d_in[6];
    const float* enc_W3 = (const float*)d_in[7];
    const float* enc_b3 = (const float*)d_in[8];
    const float* enc_W4 = (const float*)d_in[9];
    const float* enc_b4 = (const float*)d_in[10];
    const float* ds_W1  = (const float*)d_in[11];
    const float* ds_b1  = (const float*)d_in[12];
    const float* ds_W2  = (const float*)d_in[13];
    const float* ds_b2  = (const float*)d_in[14];
    const float* hd_W1  = (const float*)d_in[15];
    const float* hd_b1  = (const float*)d_in[16];
    const float* hd_W2  = (const float*)d_in[17];
    const float* hd_b2  = (const float*)d_in[18];
    float* out = (float*)d_out;

    // ---- workspace layout (~52 MB) ----
    char* ws = (char*)d_ws;
    int* perm  = (int*)ws;
    int* offs  = (int*)(ws + 16384);
    int* table = (int*)(ws + 16384 + 256);
    char* p = ws + 32768;
    unsigned short* xp = (unsigned short*)p; p += (size_t)PADROWS * 1024 * 2;
    unsigned short* h1 = (unsigned short*)p; p += (size_t)PADROWS * 2048 * 2;
    unsigned short* h2 = (unsigned short*)p; p += (size_t)PADROWS * 2048 * 2;
    unsigned short* zb = (unsigned short*)p; p += (size_t)PADROWS * 256 * 2;
    float* scat = out;   // reuse d_out as 8 MB scat scratch; fully overwritten later

    setup_kernel<<<1, 1024, 0, stream>>>(task, perm, offs, table);
    permute_cast_kernel<<<B_ROWS, 256, 0, stream>>>(x, perm, xp);

    // encoder (grouped by task; GX=40, 40%8==0 for the XCD remap)
    gemm9_kernel<0><<<dim3(MAXTILES, 32), 256, 0, stream>>>(xp, enc_W1, enc_b1, h1, offs, table, nullptr, 1024, 2048, 2048, B_ROWS, MAXTILES);
    gemm9_kernel<0><<<dim3(MAXTILES, 32), 256, 0, stream>>>(h1, enc_W2, enc_b2, h2, offs, table, nullptr, 2048, 2048, 2048, B_ROWS, MAXTILES);
    gemm9_kernel<0><<<dim3(MAXTILES, 32), 256, 0, stream>>>(h2, enc_W3, enc_b3, h1, offs, table, nullptr, 2048, 2048, 2048, B_ROWS, MAXTILES);
    gemm9_kernel<1><<<dim3(MAXTILES, 8), 256, 0, stream>>>(h1, enc_W4, enc_b4, scat, offs, table, nullptr, 2048, 512, 512, B_ROWS, MAXTILES);

    vae_kernel<<<B_ROWS, 256, 0, stream>>>(scat, eps, perm, zb);

    // decoder shared layers (ungrouped: t=0, all rows; GX=32)
    gemm9_kernel<0><<<dim3(32, 32), 256, 0, stream>>>(zb, ds_W1, ds_b1, h2, nullptr, nullptr, nullptr, 256, 2048, 2048, B_ROWS, 32);
    gemm9_kernel<0><<<dim3(32, 32), 256, 0, stream>>>(h2, ds_W2, ds_b2, h1, nullptr, nullptr, nullptr, 2048, 2048, 2048, B_ROWS, 32);

    // heads (grouped)
    gemm9_kernel<0><<<dim3(MAXTILES, 32), 256, 0, stream>>>(h1, hd_W1, hd_b1, h2, offs, table, nullptr, 2048, 2048, 2048, B_ROWS, MAXTILES);
    gemm9_kernel<2><<<dim3(MAXTILES, 16), 256, 0, stream>>>(h2, hd_W2, hd_b2, out, offs, table, perm, 2048, 1024, 1024, B_ROWS, MAXTILES);
}

// Round 10
// 670.406 us; speedup vs baseline: 1.0709x; 1.0709x over previous
//
#include <hip/hip_runtime.h>
#include <hip/hip_bf16.h>

#define T_TASKS 8
#define B_ROWS 4096
#define PADROWS 4224      // +128 so partial-tile A loads stay in-bounds
#define BM 128
#define BN 64
#define BK 32
#define MAXTILES 40       // sum over tasks of ceil(cnt/BM) <= T + B/BM = 40

typedef __attribute__((ext_vector_type(4))) float f32x4;
typedef __attribute__((ext_vector_type(8))) short bf16x8;

#define GLOAD_LDS16(g, l) __builtin_amdgcn_global_load_lds( \
    (const __attribute__((address_space(1))) void*)(g), \
    (__attribute__((address_space(3))) void*)(l), 16, 0, 0)

__device__ __forceinline__ unsigned short f32_to_bf16(float f) {
    union { float f; unsigned int u; } v; v.f = f;
    unsigned int r = v.u + 0x7FFF + ((v.u >> 16) & 1);  // RNE
    return (unsigned short)(r >> 16);
}

__device__ __forceinline__ unsigned int pack2_bf16(float lo, float hi) {
    __hip_bfloat162 h = __float22bfloat162_rn(make_float2(lo, hi));  // lo -> low 16 bits
    union { __hip_bfloat162 h; unsigned int u; } c; c.h = h;
    return c.u;
}

// ---------------- setup: counting sort by task + tile table ----------------
__global__ void setup_kernel(const int* __restrict__ task, int* __restrict__ perm,
                             int* __restrict__ offs, int* __restrict__ table) {
    __shared__ int cnt[T_TASKS];
    __shared__ int cur[T_TASKS];
    int tid = threadIdx.x;
    if (tid < T_TASKS) cnt[tid] = 0;
    __syncthreads();
    for (int b = tid; b < B_ROWS; b += blockDim.x)
        atomicAdd(&cnt[task[b]], 1);
    __syncthreads();
    if (tid == 0) {
        int o = 0;
        for (int t = 0; t < T_TASKS; ++t) { offs[t] = o; cur[t] = o; o += cnt[t]; }
        offs[T_TASKS] = o;
        int s = 0;
        for (int t = 0; t < T_TASKS; ++t) {
            int nt = (cnt[t] + BM - 1) / BM;
            for (int j = 0; j < nt; ++j) table[s++] = (t << 16) | j;
        }
        for (; s < MAXTILES; ++s) table[s] = -1;
    }
    __syncthreads();
    for (int b = tid; b < B_ROWS; b += blockDim.x) {
        int t = task[b];
        int pos = atomicAdd(&cur[t], 1);
        perm[pos] = b;
    }
}

// ---------------- permute + cast x -> bf16 ----------------
__global__ void permute_cast_kernel(const float* __restrict__ x, const int* __restrict__ perm,
                                    unsigned short* __restrict__ xp) {
    int rowp = blockIdx.x;
    int src = perm[rowp];
    const float4* xin = reinterpret_cast<const float4*>(x + (size_t)src * 1024);
    unsigned short* dst = xp + (size_t)rowp * 1024;
    int c4 = threadIdx.x;
    float4 v = xin[c4];
    ushort4 o;
    o.x = f32_to_bf16(v.x); o.y = f32_to_bf16(v.y);
    o.z = f32_to_bf16(v.z); o.w = f32_to_bf16(v.w);
    *reinterpret_cast<ushort4*>(dst + c4 * 4) = o;
}

// ---------------- VAE reparameterization ----------------
__global__ void vae_kernel(const float* __restrict__ scat, const float* __restrict__ eps,
                           const int* __restrict__ perm, unsigned short* __restrict__ z) {
    int rowp = blockIdx.x;
    int c = threadIdx.x;
    int src = perm[rowp];
    float mu = scat[(size_t)rowp * 512 + c];
    float ls = scat[(size_t)rowp * 512 + 256 + c];
    float e  = eps[(size_t)src * 256 + c];
    z[(size_t)rowp * 256 + c] = f32_to_bf16(mu + __expf(ls) * e);
}

// ---------------- grouped GEMM, f32 [K][N] weights consumed directly ----------------
// R8 structure, byte-identical except __launch_bounds__(256, 6):
//   grid gives exactly 5 blocks/CU (1280 blocks); the old bound of 4 forced a
//   second serial pass (occupancy 42%, MfmaUtil 11%, nothing saturated).
//   24 KB LDS allows 6 blocks/CU; VGPR 40 << 85 cap at 6 waves/EU.
// A: bf16 [rowp][K] grouped (padded), global_load_lds, src-XOR ((row>>1)&3), linear LDS.
// B: f32 [t][K][N] in-kernel: 8 k-strided dwords/lane (wave = 64 consecutive n,
//    coalesced 256B), cvt_pk -> ds_write_b128 at slot c^((n>>1)&3) (0 conflicts, R8).
// Pipeline: load_b(s+1) -> stage_a(s+1) -> compute(s) -> write_b(s+1) -> barrier.
// MODE 0: relu -> bf16 store; MODE 1: f32 store; MODE 2: sigmoid -> f32 scatter via perm
template<int MODE>
__global__ __launch_bounds__(256, 6)
void gemm10_kernel(const unsigned short* __restrict__ A,
                   const float* __restrict__ W,
                   const float* __restrict__ bias, void* __restrict__ dst,
                   const int* __restrict__ offs, const int* __restrict__ table,
                   const int* __restrict__ perm,
                   int K, int N, int ldd, int Btot, int GX)
{
    __shared__ unsigned short As[2][BM * BK];   // 8 KB each
    __shared__ unsigned short Bs[2][BN * BK];   // 4 KB each  (24 KB total)

    const int bxh = blockIdx.x;
    const int tid = threadIdx.x;

    // XCD-chunked bijective bx remap (GX % 8 == 0 for all launches here)
    int bx = (bxh & 7) * (GX >> 3) + (bxh >> 3);

    int t, mtile, off, cnt;
    if (table != nullptr) {
        int v = table[bx];
        if (v < 0) return;
        t = v >> 16; mtile = v & 0xFFFF;
        off = offs[t]; cnt = offs[t + 1] - off;
    } else {
        t = 0; mtile = bx; off = 0; cnt = Btot;
    }
    const int n0 = blockIdx.y * BN;

    const int lane = tid & 63;
    const int wave = tid >> 6;
    const int wr = wave >> 1, wc = wave & 1;

    // ---- A staging geometry (R6/R8-proven) ----
    const int rl   = lane >> 2;                 // 0..15 row within 16-row line
    const int csrc = ((lane & 3) ^ ((rl >> 1) & 3)) * 8;
    const unsigned short* Ab = A + ((size_t)(off + mtile * BM + rl)) * K + csrc;

    // ---- B staging geometry: n = lane, k-chunk c = wave ----
    const int bn = lane;                        // 0..63
    const int bc = wave;                        // 0..3 -> k = bc*8 .. +7
    const float* Wb = W + (size_t)t * K * N + n0 + bn;
    const int bslot = (bc ^ ((bn >> 1) & 3)) * 8;   // ushort offset of 16B slot
    float br[8];

    auto stage_a = [&](int buf, int k0) {
        #pragma unroll
        for (int jj = 0; jj < 2; ++jj) {
            int j = wave * 2 + jj;              // 0..7: A 16-row line
            GLOAD_LDS16(Ab + (size_t)(j * 16) * K + k0, &As[buf][j * 512]);
        }
    };
    auto load_b = [&](int k0) {
        const float* p = Wb + (size_t)(k0 + bc * 8) * N;
        #pragma unroll
        for (int j = 0; j < 8; ++j)
            br[j] = p[(size_t)j * N];
    };
    auto write_b = [&](int buf) {
        uint4 wv;
        wv.x = pack2_bf16(br[0], br[1]);
        wv.y = pack2_bf16(br[2], br[3]);
        wv.z = pack2_bf16(br[4], br[5]);
        wv.w = pack2_bf16(br[6], br[7]);
        *reinterpret_cast<uint4*>(&Bs[buf][bn * 32 + bslot]) = wv;
    };

    f32x4 acc[4][2];
    #pragma unroll
    for (int m = 0; m < 4; ++m)
        #pragma unroll
        for (int n = 0; n < 2; ++n)
            acc[m][n] = (f32x4){0.f, 0.f, 0.f, 0.f};

    auto compute = [&](int buf) {
        bf16x8 af[4], bfr[2];
        #pragma unroll
        for (int m = 0; m < 4; ++m) {
            int rf = wr * 64 + m * 16 + (lane & 15);
            af[m] = *reinterpret_cast<const bf16x8*>(
                &As[buf][rf * 32 + (((lane >> 4) ^ ((rf >> 1) & 3)) * 8)]);
        }
        #pragma unroll
        for (int n = 0; n < 2; ++n) {
            int nf = wc * 32 + n * 16 + (lane & 15);
            bfr[n] = *reinterpret_cast<const bf16x8*>(
                &Bs[buf][nf * 32 + (((lane >> 4) ^ ((nf >> 1) & 3)) * 8)]);
        }
        #pragma unroll
        for (int m = 0; m < 4; ++m)
            #pragma unroll
            for (int n = 0; n < 2; ++n)
                acc[m][n] = __builtin_amdgcn_mfma_f32_16x16x32_bf16(af[m], bfr[n], acc[m][n], 0, 0, 0);
    };

    // ---- prologue ----
    const int nsteps = K / BK;
    load_b(0);
    stage_a(0, 0);
    write_b(0);          // compiler waits br via vmcnt; gload_lds drains at barrier
    __syncthreads();

    int cur = 0;
    for (int s = 0; s < nsteps; ++s) {
        if (s + 1 < nsteps) {
            load_b((s + 1) * BK);            // B reg loads first (cvt waits only these)
            stage_a(cur ^ 1, (s + 1) * BK);  // A async -> LDS[next]
        }
        compute(cur);
        if (s + 1 < nsteps) write_b(cur ^ 1);
        __syncthreads();
        cur ^= 1;
    }

    // ---- epilogue ----
    const float* bt = bias + (size_t)t * N;
    #pragma unroll
    for (int n = 0; n < 2; ++n) {
        int col = n0 + wc * 32 + n * 16 + (lane & 15);
        float bv = bt[col];
        #pragma unroll
        for (int m = 0; m < 4; ++m) {
            int rbase = mtile * BM + wr * 64 + m * 16 + ((lane >> 4) << 2);
            #pragma unroll
            for (int j = 0; j < 4; ++j) {
                int local = rbase + j;
                if (local >= cnt) continue;
                float v = acc[m][n][j] + bv;
                if (MODE == 0) {
                    ((unsigned short*)dst)[(size_t)(off + local) * ldd + col] =
                        f32_to_bf16(fmaxf(v, 0.f));
                } else if (MODE == 1) {
                    ((float*)dst)[(size_t)(off + local) * ldd + col] = v;
                } else {
                    int grow = perm[off + local];
                    ((float*)dst)[(size_t)grow * ldd + col] = 1.f / (1.f + __expf(-v));
                }
            }
        }
    }
}

extern "C" void kernel_launch(void* const* d_in, const int* in_sizes, int n_in,
                              void* d_out, int out_size, void* d_ws, size_t ws_size,
                              hipStream_t stream) {
    const float* x      = (const float*)d_in[0];
    const int*   task   = (const int*)d_in[1];
    const float* eps    = (const float*)d_in[2];
    const float* enc_W1 = (const float*)d_in[3];
    const float* enc_b1 = (const float*)d_in[4];
    const float* enc_W2 = (const float*)d_in[5];
    const float* enc_b2 = (const float*)d_in[6];
    const float* enc_W3 = (const float*)d_in[7];
    const float* enc_b3 = (const float*)d_in[8];
    const float* enc_W4 = (const float*)d_in[9];
    const float* enc_b4 = (const float*)d_in[10];
    const float* ds_W1  = (const float*)d_in[11];
    const float* ds_b1  = (const float*)d_in[12];
    const float* ds_W2  = (const float*)d_in[13];
    const float* ds_b2  = (const float*)d_in[14];
    const float* hd_W1  = (const float*)d_in[15];
    const float* hd_b1  = (const float*)d_in[16];
    const float* hd_W2  = (const float*)d_in[17];
    const float* hd_b2  = (const float*)d_in[18];
    float* out = (float*)d_out;

    // ---- workspace layout (~52 MB) ----
    char* ws = (char*)d_ws;
    int* perm  = (int*)ws;
    int* offs  = (int*)(ws + 16384);
    int* table = (int*)(ws + 16384 + 256);
    char* p = ws + 32768;
    unsigned short* xp = (unsigned short*)p; p += (size_t)PADROWS * 1024 * 2;
    unsigned short* h1 = (unsigned short*)p; p += (size_t)PADROWS * 2048 * 2;
    unsigned short* h2 = (unsigned short*)p; p += (size_t)PADROWS * 2048 * 2;
    unsigned short* zb = (unsigned short*)p; p += (size_t)PADROWS * 256 * 2;
    float* scat = out;   // reuse d_out as 8 MB scat scratch; fully overwritten later

    setup_kernel<<<1, 1024, 0, stream>>>(task, perm, offs, table);
    permute_cast_kernel<<<B_ROWS, 256, 0, stream>>>(x, perm, xp);

    // encoder (grouped by task; GX=40, 40%8==0 for the XCD remap)
    gemm10_kernel<0><<<dim3(MAXTILES, 32), 256, 0, stream>>>(xp, enc_W1, enc_b1, h1, offs, table, nullptr, 1024, 2048, 2048, B_ROWS, MAXTILES);
    gemm10_kernel<0><<<dim3(MAXTILES, 32), 256, 0, stream>>>(h1, enc_W2, enc_b2, h2, offs, table, nullptr, 2048, 2048, 2048, B_ROWS, MAXTILES);
    gemm10_kernel<0><<<dim3(MAXTILES, 32), 256, 0, stream>>>(h2, enc_W3, enc_b3, h1, offs, table, nullptr, 2048, 2048, 2048, B_ROWS, MAXTILES);
    gemm10_kernel<1><<<dim3(MAXTILES, 8), 256, 0, stream>>>(h1, enc_W4, enc_b4, scat, offs, table, nullptr, 2048, 512, 512, B_ROWS, MAXTILES);

    vae_kernel<<<B_ROWS, 256, 0, stream>>>(scat, eps, perm, zb);

    // decoder shared layers (ungrouped: t=0, all rows; GX=32)
    gemm10_kernel<0><<<dim3(32, 32), 256, 0, stream>>>(zb, ds_W1, ds_b1, h2, nullptr, nullptr, nullptr, 256, 2048, 2048, B_ROWS, 32);
    gemm10_kernel<0><<<dim3(32, 32), 256, 0, stream>>>(h2, ds_W2, ds_b2, h1, nullptr, nullptr, nullptr, 2048, 2048, 2048, B_ROWS, 32);

    // heads (grouped)
    gemm10_kernel<0><<<dim3(MAXTILES, 32), 256, 0, stream>>>(h1, hd_W1, hd_b1, h2, offs, table, nullptr, 2048, 2048, 2048, B_ROWS, MAXTILES);
    gemm10_kernel<2><<<dim3(MAXTILES, 16), 256, 0, stream>>>(h2, hd_W2, hd_b2, out, offs, table, perm, 2048, 1024, 1024, B_ROWS, MAXTILES);
}

// Round 11
// 666.838 us; speedup vs baseline: 1.0766x; 1.0054x over previous
//
#include <hip/hip_runtime.h>
#include <hip/hip_bf16.h>

#define T_TASKS 8
#define B_ROWS 4096
#define PADROWS 4224      // +128 so partial-tile A loads stay in-bounds
#define BM 128
#define BN 128
#define BK 32
#define MAXTILES 40       // sum over tasks of ceil(cnt/BM) <= T + B/BM = 40

typedef __attribute__((ext_vector_type(4))) float f32x4;
typedef __attribute__((ext_vector_type(8))) short bf16x8;

#define GLOAD_LDS16(g, l) __builtin_amdgcn_global_load_lds( \
    (const __attribute__((address_space(1))) void*)(g), \
    (__attribute__((address_space(3))) void*)(l), 16, 0, 0)

__device__ __forceinline__ unsigned short f32_to_bf16(float f) {
    union { float f; unsigned int u; } v; v.f = f;
    unsigned int r = v.u + 0x7FFF + ((v.u >> 16) & 1);  // RNE
    return (unsigned short)(r >> 16);
}

__device__ __forceinline__ unsigned int pack2_bf16(float lo, float hi) {
    __hip_bfloat162 h = __float22bfloat162_rn(make_float2(lo, hi));  // lo -> low 16 bits
    union { __hip_bfloat162 h; unsigned int u; } c; c.h = h;
    return c.u;
}

// ---------------- setup: counting sort by task + tile table ----------------
__global__ void setup_kernel(const int* __restrict__ task, int* __restrict__ perm,
                             int* __restrict__ offs, int* __restrict__ table) {
    __shared__ int cnt[T_TASKS];
    __shared__ int cur[T_TASKS];
    int tid = threadIdx.x;
    if (tid < T_TASKS) cnt[tid] = 0;
    __syncthreads();
    for (int b = tid; b < B_ROWS; b += blockDim.x)
        atomicAdd(&cnt[task[b]], 1);
    __syncthreads();
    if (tid == 0) {
        int o = 0;
        for (int t = 0; t < T_TASKS; ++t) { offs[t] = o; cur[t] = o; o += cnt[t]; }
        offs[T_TASKS] = o;
        int s = 0;
        for (int t = 0; t < T_TASKS; ++t) {
            int nt = (cnt[t] + BM - 1) / BM;
            for (int j = 0; j < nt; ++j) table[s++] = (t << 16) | j;
        }
        for (; s < MAXTILES; ++s) table[s] = -1;
    }
    __syncthreads();
    for (int b = tid; b < B_ROWS; b += blockDim.x) {
        int t = task[b];
        int pos = atomicAdd(&cur[t], 1);
        perm[pos] = b;
    }
}

// ---------------- permute + cast x -> bf16 ----------------
__global__ void permute_cast_kernel(const float* __restrict__ x, const int* __restrict__ perm,
                                    unsigned short* __restrict__ xp) {
    int rowp = blockIdx.x;
    int src = perm[rowp];
    const float4* xin = reinterpret_cast<const float4*>(x + (size_t)src * 1024);
    unsigned short* dst = xp + (size_t)rowp * 1024;
    int c4 = threadIdx.x;
    float4 v = xin[c4];
    ushort4 o;
    o.x = f32_to_bf16(v.x); o.y = f32_to_bf16(v.y);
    o.z = f32_to_bf16(v.z); o.w = f32_to_bf16(v.w);
    *reinterpret_cast<ushort4*>(dst + c4 * 4) = o;
}

// ---------------- VAE reparameterization ----------------
__global__ void vae_kernel(const float* __restrict__ scat, const float* __restrict__ eps,
                           const int* __restrict__ perm, unsigned short* __restrict__ z) {
    int rowp = blockIdx.x;
    int c = threadIdx.x;
    int src = perm[rowp];
    float mu = scat[(size_t)rowp * 512 + c];
    float ls = scat[(size_t)rowp * 512 + 256 + c];
    float e  = eps[(size_t)src * 256 + c];
    z[(size_t)rowp * 256 + c] = f32_to_bf16(mu + __expf(ls) * e);
}

// ---------------- grouped GEMM, BN=128, f32 [K][N] weights consumed directly ----------------
// Regime (R10 post-mortem): time = blocks/CU x nsteps x step-latency (~1100cy, not
// BW/MFMA-bound). Fix: double per-block output (BN 64->128, 16 MFMA/step/wave) ->
// per-CU serial steps halve (320 -> 160) at ~constant step latency.
// A: bf16 [rowp][K] grouped (padded), global_load_lds, src-XOR ((row>>1)&3), linear LDS.
// B: f32 [t][K][N] in-kernel, two 64-wide n-halves (static brL/brH reg banks):
//    8 k-strided dwords/lane per half (wave = 64 consecutive n -> coalesced 256B),
//    cvt_pk -> ds_write_b128 at slot (wave^((n>>1)&3)) - R8-proven, 0 conflicts.
// 32 KB dbuf LDS; grid 640 blocks for big layers (2.5/CU); launch_bounds(256,3).
// Pipeline: load_b(s+1) -> stage_a(s+1) -> compute(s) -> write_b(s+1) -> barrier.
// MODE 0: relu -> bf16 store; MODE 1: f32 store; MODE 2: sigmoid -> f32 scatter via perm
template<int MODE>
__global__ __launch_bounds__(256, 3)
void gemm11_kernel(const unsigned short* __restrict__ A,
                   const float* __restrict__ W,
                   const float* __restrict__ bias, void* __restrict__ dst,
                   const int* __restrict__ offs, const int* __restrict__ table,
                   const int* __restrict__ perm,
                   int K, int N, int ldd, int Btot, int GX)
{
    __shared__ unsigned short As[2][BM * BK];   // 8 KB each
    __shared__ unsigned short Bs[2][BN * BK];   // 8 KB each  (32 KB total)

    const int bxh = blockIdx.x;
    const int tid = threadIdx.x;

    // XCD-chunked bijective bx remap (GX % 8 == 0 for all launches here).
    // Same bx -> same XCD across blockIdx.y since gridDim.x % 8 == 0.
    int bx = (bxh & 7) * (GX >> 3) + (bxh >> 3);

    int t, mtile, off, cnt;
    if (table != nullptr) {
        int v = table[bx];
        if (v < 0) return;
        t = v >> 16; mtile = v & 0xFFFF;
        off = offs[t]; cnt = offs[t + 1] - off;
    } else {
        t = 0; mtile = bx; off = 0; cnt = Btot;
    }
    const int n0 = blockIdx.y * BN;

    const int lane = tid & 63;
    const int wave = tid >> 6;
    const int wr = wave >> 1, wc = wave & 1;

    // ---- A staging geometry (R6/R8-proven) ----
    const int rl   = lane >> 2;                 // 0..15 row within 16-row line
    const int csrc = ((lane & 3) ^ ((rl >> 1) & 3)) * 8;
    const unsigned short* Ab = A + ((size_t)(off + mtile * BM + rl)) * K + csrc;

    // ---- B staging geometry: two n-halves, n = lane + 64*h, k-chunk = wave ----
    const int bn = lane;                        // 0..63 (half-local)
    const int bc = wave;                        // 0..3 -> k = bc*8 .. +7
    const float* Wb = W + (size_t)t * K * N + n0 + bn;
    const int slotL = (bc ^ ((bn >> 1) & 3)) * 8;          // n-half 0
    const int slotH = (bc ^ (((bn + 64) >> 1) & 3)) * 8;   // n-half 1 (same pattern)
    float brL[8], brH[8];

    auto stage_a = [&](int buf, int k0) {
        #pragma unroll
        for (int jj = 0; jj < 2; ++jj) {
            int j = wave * 2 + jj;              // 0..7: A 16-row line
            GLOAD_LDS16(Ab + (size_t)(j * 16) * K + k0, &As[buf][j * 512]);
        }
    };
    auto load_b = [&](int k0) {
        const float* p = Wb + (size_t)(k0 + bc * 8) * N;
        #pragma unroll
        for (int j = 0; j < 8; ++j) brL[j] = p[(size_t)j * N];
        #pragma unroll
        for (int j = 0; j < 8; ++j) brH[j] = p[(size_t)j * N + 64];
    };
    auto write_b = [&](int buf) {
        uint4 wv;
        wv.x = pack2_bf16(brL[0], brL[1]);
        wv.y = pack2_bf16(brL[2], brL[3]);
        wv.z = pack2_bf16(brL[4], brL[5]);
        wv.w = pack2_bf16(brL[6], brL[7]);
        *reinterpret_cast<uint4*>(&Bs[buf][bn * 32 + slotL]) = wv;
        wv.x = pack2_bf16(brH[0], brH[1]);
        wv.y = pack2_bf16(brH[2], brH[3]);
        wv.z = pack2_bf16(brH[4], brH[5]);
        wv.w = pack2_bf16(brH[6], brH[7]);
        *reinterpret_cast<uint4*>(&Bs[buf][(bn + 64) * 32 + slotH]) = wv;
    };

    f32x4 acc[4][4];
    #pragma unroll
    for (int m = 0; m < 4; ++m)
        #pragma unroll
        for (int n = 0; n < 4; ++n)
            acc[m][n] = (f32x4){0.f, 0.f, 0.f, 0.f};

    auto compute = [&](int buf) {
        bf16x8 af[4], bfr[4];
        #pragma unroll
        for (int m = 0; m < 4; ++m) {
            int rf = wr * 64 + m * 16 + (lane & 15);
            af[m] = *reinterpret_cast<const bf16x8*>(
                &As[buf][rf * 32 + (((lane >> 4) ^ ((rf >> 1) & 3)) * 8)]);
        }
        #pragma unroll
        for (int n = 0; n < 4; ++n) {
            int nf = wc * 64 + n * 16 + (lane & 15);
            bfr[n] = *reinterpret_cast<const bf16x8*>(
                &Bs[buf][nf * 32 + (((lane >> 4) ^ ((nf >> 1) & 3)) * 8)]);
        }
        #pragma unroll
        for (int m = 0; m < 4; ++m)
            #pragma unroll
            for (int n = 0; n < 4; ++n)
                acc[m][n] = __builtin_amdgcn_mfma_f32_16x16x32_bf16(af[m], bfr[n], acc[m][n], 0, 0, 0);
    };

    // ---- prologue ----
    const int nsteps = K / BK;
    load_b(0);
    stage_a(0, 0);
    write_b(0);          // compiler waits br via vmcnt; gload_lds drains at barrier
    __syncthreads();

    int cur = 0;
    for (int s = 0; s < nsteps; ++s) {
        if (s + 1 < nsteps) {
            load_b((s + 1) * BK);            // B reg loads first (cvt waits only these)
            stage_a(cur ^ 1, (s + 1) * BK);  // A async -> LDS[next]
        }
        compute(cur);
        if (s + 1 < nsteps) write_b(cur ^ 1);
        __syncthreads();
        cur ^= 1;
    }

    // ---- epilogue ----
    const float* bt = bias + (size_t)t * N;
    #pragma unroll
    for (int n = 0; n < 4; ++n) {
        int col = n0 + wc * 64 + n * 16 + (lane & 15);
        float bv = bt[col];
        #pragma unroll
        for (int m = 0; m < 4; ++m) {
            int rbase = mtile * BM + wr * 64 + m * 16 + ((lane >> 4) << 2);
            #pragma unroll
            for (int j = 0; j < 4; ++j) {
                int local = rbase + j;
                if (local >= cnt) continue;
                float v = acc[m][n][j] + bv;
                if (MODE == 0) {
                    ((unsigned short*)dst)[(size_t)(off + local) * ldd + col] =
                        f32_to_bf16(fmaxf(v, 0.f));
                } else if (MODE == 1) {
                    ((float*)dst)[(size_t)(off + local) * ldd + col] = v;
                } else {
                    int grow = perm[off + local];
                    ((float*)dst)[(size_t)grow * ldd + col] = 1.f / (1.f + __expf(-v));
                }
            }
        }
    }
}

extern "C" void kernel_launch(void* const* d_in, const int* in_sizes, int n_in,
                              void* d_out, int out_size, void* d_ws, size_t ws_size,
                              hipStream_t stream) {
    const float* x      = (const float*)d_in[0];
    const int*   task   = (const int*)d_in[1];
    const float* eps    = (const float*)d_in[2];
    const float* enc_W1 = (const float*)d_in[3];
    const float* enc_b1 = (const float*)d_in[4];
    const float* enc_W2 = (const float*)d_in[5];
    const float* enc_b2 = (const float*)d_in[6];
    const float* enc_W3 = (const float*)d_in[7];
    const float* enc_b3 = (const float*)d_in[8];
    const float* enc_W4 = (const float*)d_in[9];
    const float* enc_b4 = (const float*)d_in[10];
    const float* ds_W1  = (const float*)d_in[11];
    const float* ds_b1  = (const float*)d_in[12];
    const float* ds_W2  = (const float*)d_in[13];
    const float* ds_b2  = (const float*)d_in[14];
    const float* hd_W1  = (const float*)d_in[15];
    const float* hd_b1  = (const float*)d_in[16];
    const float* hd_W2  = (const float*)d_in[17];
    const float* hd_b2  = (const float*)d_in[18];
    float* out = (float*)d_out;

    // ---- workspace layout (~52 MB) ----
    char* ws = (char*)d_ws;
    int* perm  = (int*)ws;
    int* offs  = (int*)(ws + 16384);
    int* table = (int*)(ws + 16384 + 256);
    char* p = ws + 32768;
    unsigned short* xp = (unsigned short*)p; p += (size_t)PADROWS * 1024 * 2;
    unsigned short* h1 = (unsigned short*)p; p += (size_t)PADROWS * 2048 * 2;
    unsigned short* h2 = (unsigned short*)p; p += (size_t)PADROWS * 2048 * 2;
    unsigned short* zb = (unsigned short*)p; p += (size_t)PADROWS * 256 * 2;
    float* scat = out;   // reuse d_out as 8 MB scat scratch; fully overwritten later

    setup_kernel<<<1, 1024, 0, stream>>>(task, perm, offs, table);
    permute_cast_kernel<<<B_ROWS, 256, 0, stream>>>(x, perm, xp);

    // encoder (grouped by task; GX=40, 40%8==0 for the XCD remap)
    gemm11_kernel<0><<<dim3(MAXTILES, 16), 256, 0, stream>>>(xp, enc_W1, enc_b1, h1, offs, table, nullptr, 1024, 2048, 2048, B_ROWS, MAXTILES);
    gemm11_kernel<0><<<dim3(MAXTILES, 16), 256, 0, stream>>>(h1, enc_W2, enc_b2, h2, offs, table, nullptr, 2048, 2048, 2048, B_ROWS, MAXTILES);
    gemm11_kernel<0><<<dim3(MAXTILES, 16), 256, 0, stream>>>(h2, enc_W3, enc_b3, h1, offs, table, nullptr, 2048, 2048, 2048, B_ROWS, MAXTILES);
    gemm11_kernel<1><<<dim3(MAXTILES, 4), 256, 0, stream>>>(h1, enc_W4, enc_b4, scat, offs, table, nullptr, 2048, 512, 512, B_ROWS, MAXTILES);

    vae_kernel<<<B_ROWS, 256, 0, stream>>>(scat, eps, perm, zb);

    // decoder shared layers (ungrouped: t=0, all rows; GX=32)
    gemm11_kernel<0><<<dim3(32, 16), 256, 0, stream>>>(zb, ds_W1, ds_b1, h2, nullptr, nullptr, nullptr, 256, 2048, 2048, B_ROWS, 32);
    gemm11_kernel<0><<<dim3(32, 16), 256, 0, stream>>>(h2, ds_W2, ds_b2, h1, nullptr, nullptr, nullptr, 2048, 2048, 2048, B_ROWS, 32);

    // heads (grouped)
    gemm11_kernel<0><<<dim3(MAXTILES, 16), 256, 0, stream>>>(h1, hd_W1, hd_b1, h2, offs, table, nullptr, 2048, 2048, 2048, B_ROWS, MAXTILES);
    gemm11_kernel<2><<<dim3(MAXTILES, 8), 256, 0, stream>>>(h2, hd_W2, hd_b2, out, offs, table, perm, 2048, 1024, 1024, B_ROWS, MAXTILES);
}

// Round 12
// 618.606 us; speedup vs baseline: 1.1606x; 1.0780x over previous
//
#include <hip/hip_runtime.h>
#include <hip/hip_bf16.h>

#define T_TASKS 8
#define B_ROWS 4096
#define PADROWS 4224      // +128 so partial-tile A loads stay in-bounds
#define BM 128
#define BK 32
#define MAXTILES 40       // sum over tasks of ceil(cnt/BM) <= T + B/BM = 40

typedef __attribute__((ext_vector_type(4))) float f32x4;
typedef __attribute__((ext_vector_type(8))) short bf16x8;

#define GLOAD_LDS16(g, l) __builtin_amdgcn_global_load_lds( \
    (const __attribute__((address_space(1))) void*)(g), \
    (__attribute__((address_space(3))) void*)(l), 16, 0, 0)

struct TP { const float* src; unsigned short* dst; int K; int N; int ntiles; };

__device__ __forceinline__ unsigned short f32_to_bf16(float f) {
    union { float f; unsigned int u; } v; v.f = f;
    unsigned int r = v.u + 0x7FFF + ((v.u >> 16) & 1);  // RNE
    return (unsigned short)(r >> 16);
}

// ---------------- setup: counting sort by task + tile table ----------------
__global__ void setup_kernel(const int* __restrict__ task, int* __restrict__ perm,
                             int* __restrict__ offs, int* __restrict__ table) {
    __shared__ int cnt[T_TASKS];
    __shared__ int cur[T_TASKS];
    int tid = threadIdx.x;
    if (tid < T_TASKS) cnt[tid] = 0;
    __syncthreads();
    for (int b = tid; b < B_ROWS; b += blockDim.x)
        atomicAdd(&cnt[task[b]], 1);
    __syncthreads();
    if (tid == 0) {
        int o = 0;
        for (int t = 0; t < T_TASKS; ++t) { offs[t] = o; cur[t] = o; o += cnt[t]; }
        offs[T_TASKS] = o;
        int s = 0;
        for (int t = 0; t < T_TASKS; ++t) {
            int nt = (cnt[t] + BM - 1) / BM;
            for (int j = 0; j < nt; ++j) table[s++] = (t << 16) | j;
        }
        for (; s < MAXTILES; ++s) table[s] = -1;
    }
    __syncthreads();
    for (int b = tid; b < B_ROWS; b += blockDim.x) {
        int t = task[b];
        int pos = atomicAdd(&cur[t], 1);
        perm[pos] = b;
    }
}

// ---------------- permute + cast x -> bf16 ----------------
__global__ void permute_cast_kernel(const float* __restrict__ x, const int* __restrict__ perm,
                                    unsigned short* __restrict__ xp) {
    int rowp = blockIdx.x;
    int src = perm[rowp];
    const float4* xin = reinterpret_cast<const float4*>(x + (size_t)src * 1024);
    unsigned short* dst = xp + (size_t)rowp * 1024;
    int c4 = threadIdx.x;
    float4 v = xin[c4];
    ushort4 o;
    o.x = f32_to_bf16(v.x); o.y = f32_to_bf16(v.y);
    o.z = f32_to_bf16(v.z); o.w = f32_to_bf16(v.w);
    *reinterpret_cast<ushort4*>(dst + c4 * 4) = o;
}

// ---------------- VAE reparameterization ----------------
__global__ void vae_kernel(const float* __restrict__ scat, const float* __restrict__ eps,
                           const int* __restrict__ perm, unsigned short* __restrict__ z) {
    int rowp = blockIdx.x;
    int c = threadIdx.x;
    int src = perm[rowp];
    float mu = scat[(size_t)rowp * 512 + c];
    float ls = scat[(size_t)rowp * 512 + 256 + c];
    float e  = eps[(size_t)src * 256 + c];
    z[(size_t)rowp * 256 + c] = f32_to_bf16(mu + __expf(ls) * e);
}

// ---------------- standalone weight transpose (enc_W1 only) ----------------
__global__ __launch_bounds__(256)
void transpose_cast_kernel(const float* __restrict__ W, unsigned short* __restrict__ Wt,
                           int K, int N) {
    const size_t toff = (size_t)blockIdx.z * K * N;
    const float* Ws = W + toff;
    unsigned short* Wd = Wt + toff;
    const int k0 = blockIdx.x * 64;
    const int n0 = blockIdx.y * 64;
    __shared__ unsigned short Tt[64 * 64];
    const int tid = threadIdx.x;
    const int n = tid & 63;
    const int kq = tid >> 6;
    #pragma unroll
    for (int i = 0; i < 4; ++i) {
        int kk = kq * 16 + i * 4;
        const float* p = Ws + (size_t)(k0 + kk) * N + n0 + n;
        float v0 = p[0];
        float v1 = p[(size_t)N];
        float v2 = p[(size_t)2 * N];
        float v3 = p[(size_t)3 * N];
        unsigned int lo = (unsigned int)f32_to_bf16(v0) | ((unsigned int)f32_to_bf16(v1) << 16);
        unsigned int hi = (unsigned int)f32_to_bf16(v2) | ((unsigned int)f32_to_bf16(v3) << 16);
        int c = (kk >> 2) ^ (n & 15);
        *reinterpret_cast<uint2*>(Tt + n * 64 + c * 4) = make_uint2(lo, hi);
    }
    __syncthreads();
    #pragma unroll
    for (int it = 0; it < 2; ++it) {
        int c  = it * 256 + tid;
        int nn = c >> 3;
        int cg = c & 7;
        int c1 = (cg * 2) ^ (nn & 15);
        int c2 = (cg * 2 + 1) ^ (nn & 15);
        uint2 a = *reinterpret_cast<const uint2*>(Tt + nn * 64 + c1 * 4);
        uint2 b = *reinterpret_cast<const uint2*>(Tt + nn * 64 + c2 * 4);
        uint4 o = make_uint4(a.x, a.y, b.x, b.y);
        *reinterpret_cast<uint4*>(Wd + (size_t)(n0 + nn) * K + k0 + cg * 8) = o;
    }
}

// ---------------- fused grouped GEMM (templated BN) + transpose-role blocks ----------------
// Consolidation of all per-knob winners:
//   BN=128 (R11: fewest serial steps/CU) or BN=64 for small-N layers (grid size);
//   B: bf16 pre-transposed [t][N][K] via global_load_lds (R4/R6: 3-4 VMEM/step, no cvt burst);
//   ride-along transposes (R4/R6), XCD-chunked bx remap (R6), R6 swizzle (~0 conflicts).
// GEMM (bx < GX); transpose role (bx >= GX): up to two weight tensors, 64x64 tiles.
// MODE 0: relu -> bf16; MODE 1: f32 store; MODE 2: sigmoid -> f32 scatter via perm
template<int MODE, int BN>
__global__ __launch_bounds__(256, (BN == 64 ? 6 : 4))
void gemm12_kernel(const unsigned short* __restrict__ A,
                   const unsigned short* __restrict__ Wt,
                   const float* __restrict__ bias, void* __restrict__ dst,
                   const int* __restrict__ offs, const int* __restrict__ table,
                   const int* __restrict__ perm,
                   int K, int N, int ldd, int Btot, int GX, TP tpa, TP tpb)
{
    constexpr int NR = BN / 32;                 // acc cols per wave (2 or 4)
    __shared__ unsigned short As[2][BM * BK];   // 8 KB each
    __shared__ unsigned short Bs[2][BN * BK];   // 4/8 KB each (24/32 KB total)

    const int bxh = blockIdx.x;
    const int tid = threadIdx.x;

    if (bxh >= GX) {
        // ---------- transpose role ----------
        int tile = (bxh - GX) * gridDim.y + blockIdx.y;
        const float* src; unsigned short* dstp; int tK, tN;
        if (tile < tpa.ntiles) { src = tpa.src; dstp = tpa.dst; tK = tpa.K; tN = tpa.N; }
        else {
            tile -= tpa.ntiles;
            if (tile >= tpb.ntiles) return;
            src = tpb.src; dstp = tpb.dst; tK = tpb.K; tN = tpb.N;
        }
        int tk = tK >> 6, tn = tN >> 6;
        int z = tile / (tk * tn);
        int r = tile % (tk * tn);
        int k0 = (r % tk) * 64, n0 = (r / tk) * 64;
        const size_t toff = (size_t)z * tK * tN;
        const float* Ws = src + toff;
        unsigned short* Wd = dstp + toff;
        unsigned short* Tt = &As[0][0];
        const int n = tid & 63;
        const int kq = tid >> 6;
        #pragma unroll
        for (int i = 0; i < 4; ++i) {
            int kk = kq * 16 + i * 4;
            const float* p = Ws + (size_t)(k0 + kk) * tN + n0 + n;
            float v0 = p[0];
            float v1 = p[(size_t)tN];
            float v2 = p[(size_t)2 * tN];
            float v3 = p[(size_t)3 * tN];
            unsigned int lo = (unsigned int)f32_to_bf16(v0) | ((unsigned int)f32_to_bf16(v1) << 16);
            unsigned int hi = (unsigned int)f32_to_bf16(v2) | ((unsigned int)f32_to_bf16(v3) << 16);
            int c = (kk >> 2) ^ (n & 15);
            *reinterpret_cast<uint2*>(Tt + n * 64 + c * 4) = make_uint2(lo, hi);
        }
        __syncthreads();
        #pragma unroll
        for (int it = 0; it < 2; ++it) {
            int c  = it * 256 + tid;
            int nn = c >> 3;
            int cg = c & 7;
            int c1 = (cg * 2) ^ (nn & 15);
            int c2 = (cg * 2 + 1) ^ (nn & 15);
            uint2 a = *reinterpret_cast<const uint2*>(Tt + nn * 64 + c1 * 4);
            uint2 b = *reinterpret_cast<const uint2*>(Tt + nn * 64 + c2 * 4);
            uint4 o = make_uint4(a.x, a.y, b.x, b.y);
            *reinterpret_cast<uint4*>(Wd + (size_t)(n0 + nn) * tK + k0 + cg * 8) = o;
        }
        return;
    }

    // ---------- GEMM role ----------
    // XCD-chunked bijective bx remap (GX%8==0 and gridDim.x%8==0 in all launches)
    int bx = (bxh & 7) * (GX >> 3) + (bxh >> 3);

    int t, mtile, off, cnt;
    if (table != nullptr) {
        int v = table[bx];
        if (v < 0) return;
        t = v >> 16; mtile = v & 0xFFFF;
        off = offs[t]; cnt = offs[t + 1] - off;
    } else {
        t = 0; mtile = bx; off = 0; cnt = Btot;
    }
    const int n0 = blockIdx.y * BN;

    const int lane = tid & 63;
    const int wave = tid >> 6;
    const int wr = wave >> 1, wc = wave & 1;

    // staging geometry: lane -> row rl=lane>>2 within a 16-row line, chunk lane&3,
    // source chunk XOR ((rl>>1)&3). LDS dest linear.  (R6-proven)
    const int rl   = lane >> 2;                 // 0..15
    const int csrc = ((lane & 3) ^ ((rl >> 1) & 3)) * 8;
    const unsigned short* Ab = A + ((size_t)(off + mtile * BM + rl)) * K + csrc;
    const unsigned short* Bb = Wt + ((size_t)t * N + n0 + rl) * K + csrc;

    auto stage = [&](int buf, int k0) {
        #pragma unroll
        for (int jj = 0; jj < 2; ++jj) {
            int j = wave * 2 + jj;              // 0..7: A 16-row line
            GLOAD_LDS16(Ab + (size_t)(j * 16) * K + k0, &As[buf][j * 512]);
        }
        #pragma unroll
        for (int jb = 0; jb < BN / 64; ++jb) {
            int j = wave * (BN / 64) + jb;      // B 16-row line
            GLOAD_LDS16(Bb + (size_t)(j * 16) * K + k0, &Bs[buf][j * 512]);
        }
    };

    f32x4 acc[4][NR];
    #pragma unroll
    for (int m = 0; m < 4; ++m)
        #pragma unroll
        for (int n = 0; n < NR; ++n)
            acc[m][n] = (f32x4){0.f, 0.f, 0.f, 0.f};

    auto compute = [&](int buf) {
        bf16x8 af[4], bfr[NR];
        #pragma unroll
        for (int m = 0; m < 4; ++m) {
            int rf = wr * 64 + m * 16 + (lane & 15);
            af[m] = *reinterpret_cast<const bf16x8*>(
                &As[buf][rf * 32 + (((lane >> 4) ^ ((rf >> 1) & 3)) * 8)]);
        }
        #pragma unroll
        for (int n = 0; n < NR; ++n) {
            int nf = wc * (BN / 2) + n * 16 + (lane & 15);
            bfr[n] = *reinterpret_cast<const bf16x8*>(
                &Bs[buf][nf * 32 + (((lane >> 4) ^ ((nf >> 1) & 3)) * 8)]);
        }
        #pragma unroll
        for (int m = 0; m < 4; ++m)
            #pragma unroll
            for (int n = 0; n < NR; ++n)
                acc[m][n] = __builtin_amdgcn_mfma_f32_16x16x32_bf16(af[m], bfr[n], acc[m][n], 0, 0, 0);
    };

    const int nsteps = K / BK;
    stage(0, 0);
    __syncthreads();
    int cur = 0;
    for (int s = 0; s < nsteps; ++s) {
        if (s + 1 < nsteps) stage(cur ^ 1, (s + 1) * BK);   // issue-early: hides under compute
        compute(cur);
        __syncthreads();                                    // drains stage(next) + frag reads
        cur ^= 1;
    }

    // ---- epilogue ----
    const float* bt = bias + (size_t)t * N;
    #pragma unroll
    for (int n = 0; n < NR; ++n) {
        int col = n0 + wc * (BN / 2) + n * 16 + (lane & 15);
        float bv = bt[col];
        #pragma unroll
        for (int m = 0; m < 4; ++m) {
            int rbase = mtile * BM + wr * 64 + m * 16 + ((lane >> 4) << 2);
            #pragma unroll
            for (int j = 0; j < 4; ++j) {
                int local = rbase + j;
                if (local >= cnt) continue;
                float v = acc[m][n][j] + bv;
                if (MODE == 0) {
                    ((unsigned short*)dst)[(size_t)(off + local) * ldd + col] =
                        f32_to_bf16(fmaxf(v, 0.f));
                } else if (MODE == 1) {
                    ((float*)dst)[(size_t)(off + local) * ldd + col] = v;
                } else {
                    int grow = perm[off + local];
                    ((float*)dst)[(size_t)grow * ldd + col] = 1.f / (1.f + __expf(-v));
                }
            }
        }
    }
}

extern "C" void kernel_launch(void* const* d_in, const int* in_sizes, int n_in,
                              void* d_out, int out_size, void* d_ws, size_t ws_size,
                              hipStream_t stream) {
    const float* x      = (const float*)d_in[0];
    const int*   task   = (const int*)d_in[1];
    const float* eps    = (const float*)d_in[2];
    const float* enc_W1 = (const float*)d_in[3];
    const float* enc_b1 = (const float*)d_in[4];
    const float* enc_W2 = (const float*)d_in[5];
    const float* enc_b2 = (const float*)d_in[6];
    const float* enc_W3 = (const float*)d_in[7];
    const float* enc_b3 = (const float*)d_in[8];
    const float* enc_W4 = (const float*)d_in[9];
    const float* enc_b4 = (const float*)d_in[10];
    const float* ds_W1  = (const float*)d_in[11];
    const float* ds_b1  = (const float*)d_in[12];
    const float* ds_W2  = (const float*)d_in[13];
    const float* ds_b2  = (const float*)d_in[14];
    const float* hd_W1  = (const float*)d_in[15];
    const float* hd_b1  = (const float*)d_in[16];
    const float* hd_W2  = (const float*)d_in[17];
    const float* hd_b2  = (const float*)d_in[18];
    float* out = (float*)d_out;

    // ---- workspace layout (~365 MB) ----
    char* ws = (char*)d_ws;
    int* perm  = (int*)ws;
    int* offs  = (int*)(ws + 16384);
    int* table = (int*)(ws + 16384 + 256);
    char* p = ws + 32768;
    unsigned short* xp = (unsigned short*)p; p += (size_t)PADROWS * 1024 * 2;
    unsigned short* h1 = (unsigned short*)p; p += (size_t)PADROWS * 2048 * 2;
    unsigned short* h2 = (unsigned short*)p; p += (size_t)PADROWS * 2048 * 2;
    unsigned short* zb = (unsigned short*)p; p += (size_t)PADROWS * 256 * 2;
    unsigned short* tw1  = (unsigned short*)p; p += (size_t)8 * 2048 * 1024 * 2;
    unsigned short* tw2  = (unsigned short*)p; p += (size_t)8 * 2048 * 2048 * 2;
    unsigned short* tw3  = (unsigned short*)p; p += (size_t)8 * 2048 * 2048 * 2;
    unsigned short* tw4  = (unsigned short*)p; p += (size_t)8 * 512 * 2048 * 2;
    unsigned short* tds1 = (unsigned short*)p; p += (size_t)2048 * 256 * 2;
    unsigned short* tds2 = (unsigned short*)p; p += (size_t)2048 * 2048 * 2;
    unsigned short* thd1 = (unsigned short*)p; p += (size_t)8 * 2048 * 2048 * 2;
    unsigned short* thd2 = (unsigned short*)p; p += (size_t)8 * 1024 * 2048 * 2;
    float* scat = out;   // reuse d_out as 8 MB scat scratch; fully overwritten later

    const TP tnone = { nullptr, nullptr, 64, 64, 0 };
    const TP tpW2  = { enc_W2, tw2, 2048, 2048, 8192 };
    const TP tpW3  = { enc_W3, tw3, 2048, 2048, 8192 };
    const TP tpW4  = { enc_W4, tw4, 2048,  512, 2048 };
    const TP tpDS1 = { ds_W1, tds1,  256, 2048,  128 };
    const TP tpDS2 = { ds_W2, tds2, 2048, 2048, 1024 };
    const TP tpHD1 = { hd_W1, thd1, 2048, 2048, 8192 };
    const TP tpHD2 = { hd_W2, thd2, 2048, 1024, 4096 };

    setup_kernel<<<1, 1024, 0, stream>>>(task, perm, offs, table);
    permute_cast_kernel<<<B_ROWS, 256, 0, stream>>>(x, perm, xp);

    // enc_W1 must be ready before the first GEMM -> standalone transpose
    transpose_cast_kernel<<<dim3(16, 32, 8), 256, 0, stream>>>(enc_W1, tw1, 1024, 2048);

    // All gridDim.x %8==0 (XCD remap validity).
    // D1: enc1 (BN128, y16) + transpose enc_W2 (8192/16=512) -> 552
    gemm12_kernel<0, 128><<<dim3(552, 16), 256, 0, stream>>>(xp, tw1, enc_b1, h1, offs, table, nullptr, 1024, 2048, 2048, B_ROWS, MAXTILES, tpW2, tnone);
    // D2: enc2 + transpose enc_W3 -> 552
    gemm12_kernel<0, 128><<<dim3(552, 16), 256, 0, stream>>>(h1, tw2, enc_b2, h2, offs, table, nullptr, 2048, 2048, 2048, B_ROWS, MAXTILES, tpW3, tnone);
    // D3: enc3 + transpose enc_W4 (2048) + ds_W1 (128): 2176/16=136 -> 176
    gemm12_kernel<0, 128><<<dim3(176, 16), 256, 0, stream>>>(h2, tw3, enc_b3, h1, offs, table, nullptr, 2048, 2048, 2048, B_ROWS, MAXTILES, tpW4, tpDS1);
    // D4: enc4 (BN64, N=512, y8) + transpose ds_W2 (1024/8=128) -> 168
    gemm12_kernel<1, 64><<<dim3(168, 8), 256, 0, stream>>>(h1, tw4, enc_b4, scat, offs, table, nullptr, 2048, 512, 512, B_ROWS, MAXTILES, tpDS2, tnone);

    vae_kernel<<<B_ROWS, 256, 0, stream>>>(scat, eps, perm, zb);

    // D5: ds1 (ungrouped GX=32, K=256, BN128, y16) + transpose hd_W1 (8192/16=512) -> 544
    gemm12_kernel<0, 128><<<dim3(544, 16), 256, 0, stream>>>(zb, tds1, ds_b1, h2, nullptr, nullptr, nullptr, 256, 2048, 2048, B_ROWS, 32, tpHD1, tnone);
    // D6: ds2 (ungrouped) + transpose hd_W2 (4096/16=256) -> 288
    gemm12_kernel<0, 128><<<dim3(288, 16), 256, 0, stream>>>(h2, tds2, ds_b2, h1, nullptr, nullptr, nullptr, 2048, 2048, 2048, B_ROWS, 32, tpHD2, tnone);

    // D7: hd1 (grouped, pure)
    gemm12_kernel<0, 128><<<dim3(MAXTILES, 16), 256, 0, stream>>>(h1, thd1, hd_b1, h2, offs, table, nullptr, 2048, 2048, 2048, B_ROWS, MAXTILES, tnone, tnone);
    // D8: hd2 (grouped, sigmoid scatter, BN64, y16) -> 40
    gemm12_kernel<2, 64><<<dim3(MAXTILES, 16), 256, 0, stream>>>(h2, thd2, hd_b2, out, offs, table, perm, 2048, 1024, 1024, B_ROWS, MAXTILES, tnone, tnone);
}